// Round 1
// baseline (759.621 us; speedup 1.0000x reference)
//
#include <hip/hip_runtime.h>

#define Himg 135
#define Wimg 240
#define Bimg 128
#define Cimg 3
#define BCN (Bimg*Cimg)
#define CHW (Cimg*Himg*Wimg)
#define EPSF 1e-10f

// ws layout (floats): [0,384) num accum, [384,768) den accum, [768,896) per-image dots

template<int N>
__global__ __launch_bounds__(256) void vif_scale_kernel(
    const float* __restrict__ recons,
    const float* __restrict__ x,
    float* __restrict__ numg,
    float* __restrict__ deng)
{
  constexpr int OWt = Wimg - N + 1;   // full valid output width
  constexpr int OC  = OWt / 2;        // per-block output columns (even for all N)
  constexpr int IW  = OC + N - 1;     // input columns needed
  constexpr int NS  = N + 1;          // ring slots

  __shared__ float uwin[N];
  __shared__ float chan[2*5*IW];      // [row2][chan][col]
  __shared__ float ring[5*NS*OC];     // [chan][slot][col]
  __shared__ float red[8];

  const int tid   = threadIdx.x;
  const int blk   = blockIdx.x;
  const int ctile = blk & 1;
  const int bc    = blk >> 1;
  const int x0    = ctile * OC;
  const float* rimg = recons + (size_t)bc * (Himg*Wimg);
  const float* pimg = x      + (size_t)bc * (Himg*Wimg);

  // 1D gaussian factor, normalized so outer(u,u) == reference 2D kernel
  if (tid == 0) {
    float w1[N]; float ssum = 0.f;
    const float sig = (float)N / 5.0f;
    const float inv = 1.0f / (2.0f*sig*sig);
    #pragma unroll
    for (int i = 0; i < N; ++i) {
      float d = (float)(i - N/2);
      w1[i] = expf(-d*d*inv);
      ssum += w1[i];
    }
    #pragma unroll
    for (int i = 0; i < N; ++i) uwin[i] = w1[i]/ssum;
  }
  __syncthreads();
  float u[N];
  #pragma unroll
  for (int i = 0; i < N; ++i) u[i] = uwin[i];

  const bool stageValid = tid < 2*IW;
  const int  rowS = tid / IW;
  const int  colS = tid - rowS*IW;
  const bool vValid = tid < 2*OC;
  const int  r2v  = tid / OC;
  const int  xov  = tid - r2v*OC;

  float numAcc = 0.f, denAcc = 0.f;

  for (int y0 = 0; y0 < Himg; y0 += 2) {
    // ---- stage two input rows: r, p, r^2, p^2, r*p ----
    if (stageValid) {
      int y = y0 + rowS;
      if (y < Himg) {
        int gi = y*Wimg + x0 + colS;
        float rv = rimg[gi];
        float pv = pimg[gi];
        float* cr = chan + rowS*(5*IW) + colS;
        cr[0]    = rv;
        cr[IW]   = pv;
        cr[2*IW] = rv*rv;
        cr[3*IW] = pv*pv;
        cr[4*IW] = rv*pv;
      }
    }
    __syncthreads();
    // ---- horizontal conv into ring ----
    for (int t = tid; t < 2*5*OC; t += 256) {
      int r2  = t / (5*OC);
      int rem = t - r2*(5*OC);
      int c   = rem / OC;
      int xo  = rem - c*OC;
      int y   = y0 + r2;
      if (y < Himg) {
        const float* cp = chan + (r2*5 + c)*IW + xo;
        float acc = 0.f;
        #pragma unroll
        for (int i = 0; i < N; ++i) acc = fmaf(u[i], cp[i], acc);
        ring[(c*NS + (y % NS))*OC + xo] = acc;
      }
    }
    __syncthreads();
    // ---- vertical conv + VIF pointwise for output rows y0+1-N, y0+2-N ----
    if (vValid) {
      int j = y0 + 1 - N + r2v;
      if (j >= 0 && j <= Himg - N) {
        float a0=0.f,a1=0.f,a2=0.f,a3=0.f,a4=0.f;
        int slot = j % NS;
        #pragma unroll
        for (int i = 0; i < N; ++i) {
          const float* rp = ring + slot*OC + xov;
          float w = u[i];
          a0 = fmaf(w, rp[0],       a0);
          a1 = fmaf(w, rp[NS*OC],   a1);
          a2 = fmaf(w, rp[2*NS*OC], a2);
          a3 = fmaf(w, rp[3*NS*OC], a3);
          a4 = fmaf(w, rp[4*NS*OC], a4);
          slot = (slot + 1 == NS) ? 0 : slot + 1;
        }
        float sGT = fmaxf(a2 - a0*a0, 0.f);
        float sP  = fmaxf(a3 - a1*a1, 0.f);
        float sGP = a4 - a0*a1;
        float g  = sGP / (sGT + EPSF);
        float sv = sP - g*sGP;
        if (sGT < EPSF) { g = 0.f; sv = sP; sGT = 0.f; }
        if (sP  < EPSF) { g = 0.f; sv = 0.f; }
        if (g < 0.f)    { sv = sP; g = 0.f; }
        if (sv <= EPSF) sv = EPSF;
        numAcc += __log10f(1.f + g*g*sGT/(sv + 2.0f));
        denAcc += __log10f(1.f + sGT*0.5f);
      }
    }
    // next iteration's stage-sync orders vertical reads vs. ring overwrite
  }

  // block reduction
  #pragma unroll
  for (int off = 32; off > 0; off >>= 1) {
    numAcc += __shfl_down(numAcc, off);
    denAcc += __shfl_down(denAcc, off);
  }
  const int lane = tid & 63, wid = tid >> 6;
  if (lane == 0) { red[wid] = numAcc; red[4+wid] = denAcc; }
  __syncthreads();
  if (tid == 0) {
    atomicAdd(&numg[bc], red[0]+red[1]+red[2]+red[3]);
    atomicAdd(&deng[bc], red[4]+red[5]+red[6]+red[7]);
  }
}

// per-image dot: s[b] = sum_i (x[b,i]-r[b,i]) * W[i]   (b-bias cancels; it is zeros)
__global__ __launch_bounds__(256) void dot_kernel(
    const float* __restrict__ r, const float* __restrict__ x,
    const float* __restrict__ Wl, float* __restrict__ dots)
{
  const int b = blockIdx.x;
  const int tid = threadIdx.x;
  const float4* r4 = (const float4*)(r + (size_t)b*CHW);
  const float4* x4 = (const float4*)(x + (size_t)b*CHW);
  const float4* w4 = (const float4*)Wl;
  float acc = 0.f;
  for (int i = tid; i < CHW/4; i += 256) {
    float4 rv = r4[i], xv = x4[i], wv = w4[i];
    acc += (xv.x - rv.x)*wv.x + (xv.y - rv.y)*wv.y
         + (xv.z - rv.z)*wv.z + (xv.w - rv.w)*wv.w;
  }
  #pragma unroll
  for (int off = 32; off > 0; off >>= 1) acc += __shfl_down(acc, off);
  __shared__ float red[4];
  const int lane = tid & 63, wid = tid >> 6;
  if (lane == 0) red[wid] = acc;
  __syncthreads();
  if (tid == 0) dots[b] = red[0]+red[1]+red[2]+red[3];
}

__global__ __launch_bounds__(128) void finalize_kernel(
    const float* __restrict__ ws, float* __restrict__ out)
{
  __shared__ float s1[128], s2[128];
  const int t = threadIdx.x;   // 0..127, one per image
  float d = ws[768 + t];
  float psq = d*d;
  float vimg = 0.f;
  #pragma unroll
  for (int c = 0; c < 3; ++c) {
    int bc = t*3 + c;
    vimg += ws[bc] / ws[384 + bc];
  }
  float rl = 1.f - vimg * (1.f/3.f);
  s1[t] = psq; s2[t] = rl;
  __syncthreads();
  for (int off = 64; off > 0; off >>= 1) {
    if (t < off) { s1[t] += s1[t+off]; s2[t] += s2[t+off]; }
    __syncthreads();
  }
  if (t == 0) {
    float pred = s1[0] * (1.f/128.f);
    float rec  = s2[0] * (1.f/128.f);
    out[0] = pred + rec;   // loss
    out[1] = rec;          // recons_loss
    out[2] = pred;         // prediction_loss
  }
}

extern "C" void kernel_launch(void* const* d_in, const int* in_sizes, int n_in,
                              void* d_out, int out_size, void* d_ws, size_t ws_size,
                              hipStream_t stream) {
  const float* recons = (const float*)d_in[0];
  const float* x      = (const float*)d_in[1];
  const float* Wl     = (const float*)d_in[2];
  float* ws  = (float*)d_ws;
  float* out = (float*)d_out;

  // zero num/den accumulators (ws is poisoned 0xAA before every call)
  hipMemsetAsync(d_ws, 0, 768*sizeof(float), stream);

  dot_kernel<<<Bimg, 256, 0, stream>>>(recons, x, Wl, ws + 768);

  vif_scale_kernel<17><<<BCN*2, 256, 0, stream>>>(recons, x, ws, ws + 384);
  vif_scale_kernel< 9><<<BCN*2, 256, 0, stream>>>(recons, x, ws, ws + 384);
  vif_scale_kernel< 5><<<BCN*2, 256, 0, stream>>>(recons, x, ws, ws + 384);
  vif_scale_kernel< 3><<<BCN*2, 256, 0, stream>>>(recons, x, ws, ws + 384);

  finalize_kernel<<<1, 128, 0, stream>>>(ws, out);
}